// Round 5
// baseline (1216.180 us; speedup 1.0000x reference)
//
#include <hip/hip_runtime.h>

// Problem constants (from reference)
#define E_N    800000
#define NODES  50000
#define NC     128     // node channels
#define EC     64      // edge channels
#define H1     128     // edge MLP hidden
#define O2E    64      // edge MLP out
#define NK1    192     // NC + EC (node MLP layer-1 fan-in)
#define NTILES (E_N / 32)

// clang's AMDGPU builtins use __fp16 ext-vectors
typedef __fp16 half2_t __attribute__((ext_vector_type(2)));
typedef __fp16 half4_t __attribute__((ext_vector_type(4)));
typedef float  f32x4   __attribute__((ext_vector_type(4)));

// ---------- helpers ----------
__device__ __forceinline__ unsigned short f2h_rne(float f) {
    union { _Float16 h; unsigned short s; } v; v.h = (_Float16)f; return v.s;
}
__device__ __forceinline__ float h2f(unsigned short s) {
    union { unsigned short s; _Float16 h; } v; v.s = s; return (float)v.h;
}
__device__ __forceinline__ unsigned int packh2(float a, float b) {
    return (unsigned int)f2h_rne(a) | ((unsigned int)f2h_rne(b) << 16);
}
__device__ __forceinline__ unsigned int pkrtz(float a, float b) {
    union { half2_t h; unsigned int u; } v;
    v.h = __builtin_amdgcn_cvt_pkrtz(a, b);
    return v.u;
}
__device__ __forceinline__ half2_t u2h2(unsigned int u) {
    union { unsigned int u; half2_t h; } v; v.u = u; return v.h;
}
// packed f16 add: v_pk_add_f16
__device__ __forceinline__ unsigned int hadd2(unsigned int a, unsigned int b) {
    union { unsigned int u; half2_t h; } x, y;
    x.u = a; y.u = b; x.h = x.h + y.h; return x.u;
}
#define FDOT2(a, b, c) __builtin_amdgcn_fdot2(u2h2(a), u2h2(b), (c), false)
#define MFMA16(a, b, c) __builtin_amdgcn_mfma_f32_16x16x16f16((a), (b), (c), 0, 0, 0)

__device__ __forceinline__ float silu_f(float x) { return x / (1.0f + __expf(-x)); }

// =====================================================================
// Precompute kernel (unchanged): PA = xn@W1a + b1, PB = xn@W1b, f16.
// =====================================================================
__global__ __launch_bounds__(256, 2) void pre_kernel(
    const float* __restrict__ xn,
    const float* __restrict__ eW1,
    const float* __restrict__ eb1,
    unsigned short* __restrict__ pa,   // [NODES,128] f16
    unsigned short* __restrict__ pb)   // [NODES,128] f16
{
    const int t    = threadIdx.x;
    const int col  = t & 127;
    const int half = t >> 7;
    const int row0 = half * NC;

    float w[128];
    #pragma unroll
    for (int k = 0; k < 128; ++k)
        w[k] = eW1[(size_t)(row0 + k) * H1 + col];
    const float bias = half ? 0.0f : eb1[col];

    __shared__ __align__(16) float4 sx[NC / 4];

    unsigned short* __restrict__ dst = half ? pb : pa;

    float4 x4a = make_float4(0.f, 0.f, 0.f, 0.f);
    if (t < 32) x4a = ((const float4*)(xn + (size_t)blockIdx.x * NC))[t];

    for (int v = blockIdx.x; v < NODES; v += gridDim.x) {
        const int vn    = v + gridDim.x;
        const int vload = (vn < NODES) ? vn : v;
        if (t < 32) {
            sx[t] = x4a;
            x4a = ((const float4*)(xn + (size_t)vload * NC))[t];
        }
        __syncthreads();

        float a0 = 0.f, a1 = 0.f, a2 = 0.f, a3 = 0.f;
        #pragma unroll
        for (int j = 0; j < 32; ++j) {
            float4 x = sx[j];
            a0 = fmaf(w[4 * j + 0], x.x, a0);
            a1 = fmaf(w[4 * j + 1], x.y, a1);
            a2 = fmaf(w[4 * j + 2], x.z, a2);
            a3 = fmaf(w[4 * j + 3], x.w, a3);
        }
        float r = (a0 + a1) + (a2 + a3) + bias;
        dst[(size_t)v * NC + col] = f2h_rne(r);
        __syncthreads();
    }
}

// =====================================================================
// Edge kernel — MFMA, 32-edge tiles.
//   hT[128c x 32e] = W1c^T (A, regs) . xe^T (B, LDS)   [mfma 16x16x16 f16]
//   h   = silu(hT + PA[snd] + PB[rcv])                 (psum staged in LDS)
//   oT[64 x 32e]   = W2^T (A, regs)  . h (B, LDS)
//   out_e = silu(oT + b2);  aggr[rcv] += out_e (atomics)
// Layouts (v_mfma_f32_16x16x16_f16, lane l, g = l>>4, l16 = l&15):
//   A: row=l16, k=4g+i   B: col=l16, k=4g+i   C/D: col=l16, row=4g+reg
// Wave w: GEMM1 m-tiles {2w,2w+1} x n-tiles {0,1}; GEMM2 m-tile w x n {0,1}.
// LDS rows padded (36/68 dwords) -> <=2-way bank conflicts.
// Prefetch: next tile's ei/pa/pb/xe loaded to regs during current compute.
// =====================================================================
__global__ __launch_bounds__(256, 4) void edge_kernel(
    const float* __restrict__ xe,
    const int* __restrict__ ei,
    const unsigned short* __restrict__ pa,   // [NODES,128] f16 (incl. b1)
    const unsigned short* __restrict__ pb,   // [NODES,128] f16
    const float* __restrict__ eW1,           // W1c = rows 256..319
    const float* __restrict__ eW2,
    const float* __restrict__ eb2,
    float* __restrict__ out_e,               // [E_N, 64] f32
    float* __restrict__ aggr)                // [NODES, 64] f32 (pre-zeroed)
{
    const int t   = threadIdx.x;
    const int l   = t & 63;
    const int w   = t >> 6;          // wave 0..3
    const int l16 = l & 15;
    const int g   = l >> 4;          // 0..3
    const int es  = t >> 3;          // staging edge 0..31
    const int d   = t & 7;           // staging chunk 0..7

    // ---- A fragments (constant weights) ----
    half4_t a1[2][4];                // GEMM1: m in {2w,2w+1}, ks 0..3
    #pragma unroll
    for (int m = 0; m < 2; ++m) {
        const int ch = (2 * w + m) * 16 + l16;
        #pragma unroll
        for (int ks = 0; ks < 4; ++ks) {
            #pragma unroll
            for (int i = 0; i < 4; ++i)
                a1[m][ks][i] = (__fp16)eW1[(size_t)(256 + ks * 16 + 4 * g + i) * H1 + ch];
        }
    }
    half4_t a2[8];                   // GEMM2: m-tile w, ks 0..7
    {
        const int o = w * 16 + l16;
        #pragma unroll
        for (int ks = 0; ks < 8; ++ks)
            #pragma unroll
            for (int i = 0; i < 4; ++i)
                a2[ks][i] = (__fp16)eW2[(size_t)(ks * 16 + 4 * g + i) * O2E + o];
    }
    const int o0 = w * 16 + 4 * g;
    float b2b[4];
    #pragma unroll
    for (int r = 0; r < 4; ++r) b2b[r] = eb2[o0 + r];

    // ---- LDS (padded rows: xe 36, psum/h 68 dwords) ----
    __shared__ __align__(16) unsigned int xe_lds[32 * 36];  //  4.6 KB
    __shared__ __align__(16) unsigned int ps_lds[32 * 68];  //  8.7 KB
    __shared__ __align__(16) unsigned int h_lds [32 * 68];  //  8.7 KB
    __shared__ int rcv_lds[32];

    // ---- prefetch registers ----
    uint4 pa0, pa1, pb0, pb1;
    float4 xf0, xf1;
    int rcv_r = 0;

    {   // prologue: prefetch tile blockIdx.x
        const int en  = blockIdx.x * 32 + es;
        const int snd = ei[en];
        rcv_r = ei[E_N + en];
        const uint4* par = (const uint4*)(pa + (size_t)snd * NC);
        pa0 = par[d * 2]; pa1 = par[d * 2 + 1];
        const uint4* pbr = (const uint4*)(pb + (size_t)rcv_r * NC);
        pb0 = pbr[d * 2]; pb1 = pbr[d * 2 + 1];
        const float4* xr = (const float4*)(xe + (size_t)en * EC);
        xf0 = xr[d * 2]; xf1 = xr[d * 2 + 1];
    }

    for (int tl = blockIdx.x; tl < NTILES; tl += gridDim.x) {
        // ---- stage prefetched tile into LDS ----
        {
            uint4 xp;
            xp.x = pkrtz(xf0.x, xf0.y); xp.y = pkrtz(xf0.z, xf0.w);
            xp.z = pkrtz(xf1.x, xf1.y); xp.w = pkrtz(xf1.z, xf1.w);
            *(uint4*)&xe_lds[es * 36 + d * 4] = xp;
            uint4 s0, s1;
            s0.x = hadd2(pa0.x, pb0.x); s0.y = hadd2(pa0.y, pb0.y);
            s0.z = hadd2(pa0.z, pb0.z); s0.w = hadd2(pa0.w, pb0.w);
            s1.x = hadd2(pa1.x, pb1.x); s1.y = hadd2(pa1.y, pb1.y);
            s1.z = hadd2(pa1.z, pb1.z); s1.w = hadd2(pa1.w, pb1.w);
            *(uint4*)&ps_lds[es * 68 + d * 8]     = s0;
            *(uint4*)&ps_lds[es * 68 + d * 8 + 4] = s1;
            if (d == 0) rcv_lds[es] = rcv_r;
        }
        __syncthreads();   // B1: xe/psum/rcv staged

        // ---- issue next tile's prefetch (lands during compute) ----
        const int tn = tl + (int)gridDim.x;
        if (tn < NTILES) {
            const int en  = tn * 32 + es;
            const int snd = ei[en];
            rcv_r = ei[E_N + en];
            const uint4* par = (const uint4*)(pa + (size_t)snd * NC);
            pa0 = par[d * 2]; pa1 = par[d * 2 + 1];
            const uint4* pbr = (const uint4*)(pb + (size_t)rcv_r * NC);
            pb0 = pbr[d * 2]; pb1 = pbr[d * 2 + 1];
            const float4* xr = (const float4*)(xe + (size_t)en * EC);
            xf0 = xr[d * 2]; xf1 = xr[d * 2 + 1];
        }

        // ---- GEMM1: hT = W1c^T . xe^T  (16 MFMA/wave) ----
        f32x4 acc[2][2];
        #pragma unroll
        for (int m = 0; m < 2; ++m)
            #pragma unroll
            for (int n = 0; n < 2; ++n)
                acc[m][n] = (f32x4){0.f, 0.f, 0.f, 0.f};
        #pragma unroll
        for (int n = 0; n < 2; ++n) {
            const unsigned int* xrow = &xe_lds[(n * 16 + l16) * 36];
            #pragma unroll
            for (int ks = 0; ks < 4; ++ks) {
                half4_t b = *(const half4_t*)&xrow[ks * 8 + 2 * g];
                acc[0][n] = MFMA16(a1[0][ks], b, acc[0][n]);
                acc[1][n] = MFMA16(a1[1][ks], b, acc[1][n]);
            }
        }
        // ---- epilogue1: h = silu(acc + psum); write h to LDS ----
        #pragma unroll
        for (int m = 0; m < 2; ++m) {
            const int chu = (2 * w + m) * 8 + 2 * g;   // dword index of ch0
            #pragma unroll
            for (int n = 0; n < 2; ++n) {
                const int erow = n * 16 + l16;
                union { uint2 u; unsigned short s[4]; } pu;
                pu.u = *(const uint2*)&ps_lds[erow * 68 + chu];
                float h0 = silu_f(acc[m][n][0] + h2f(pu.s[0]));
                float h1 = silu_f(acc[m][n][1] + h2f(pu.s[1]));
                float h2 = silu_f(acc[m][n][2] + h2f(pu.s[2]));
                float h3 = silu_f(acc[m][n][3] + h2f(pu.s[3]));
                uint2 hp; hp.x = pkrtz(h0, h1); hp.y = pkrtz(h2, h3);
                *(uint2*)&h_lds[erow * 68 + chu] = hp;
            }
        }
        __syncthreads();   // B2: h ready

        // ---- GEMM2: oT = W2^T . h  (16 MFMA/wave) ----
        f32x4 acc2[2];
        acc2[0] = (f32x4){0.f, 0.f, 0.f, 0.f};
        acc2[1] = (f32x4){0.f, 0.f, 0.f, 0.f};
        #pragma unroll
        for (int n = 0; n < 2; ++n) {
            const unsigned int* hrow = &h_lds[(n * 16 + l16) * 68];
            #pragma unroll
            for (int ks = 0; ks < 8; ++ks) {
                half4_t b = *(const half4_t*)&hrow[ks * 8 + 2 * g];
                acc2[n] = MFMA16(a2[ks], b, acc2[n]);
            }
        }
        // ---- epilogue2: silu + bias; store out_e; atomic aggr ----
        #pragma unroll
        for (int n = 0; n < 2; ++n) {
            const int erow = n * 16 + l16;
            const int eg   = tl * 32 + erow;
            const int rcv  = rcv_lds[erow];
            float4 ov;
            ov.x = silu_f(acc2[n][0] + b2b[0]);
            ov.y = silu_f(acc2[n][1] + b2b[1]);
            ov.z = silu_f(acc2[n][2] + b2b[2]);
            ov.w = silu_f(acc2[n][3] + b2b[3]);
            *(float4*)&out_e[(size_t)eg * O2E + o0] = ov;
            float* ag = &aggr[(size_t)rcv * O2E + o0];
            unsafeAtomicAdd(ag + 0, ov.x);
            unsafeAtomicAdd(ag + 1, ov.y);
            unsafeAtomicAdd(ag + 2, ov.z);
            unsafeAtomicAdd(ag + 3, ov.w);
        }
        __syncthreads();   // B3: protect xe/ps/rcv LDS before next staging
        // Races: xe/ps read pre-B2, next write post-B3 (B2,B3 between).
        //        h written pre-B2, read pre-B3; next write after B3+B1'.
        //        rcv read pre-B3, next write post-B3.
    }
}

// =====================================================================
// Node kernel (unchanged from round 4): f16-dot2, prefetched staging.
// =====================================================================
__global__ __launch_bounds__(256, 3) void node_kernel(
    const float* __restrict__ xn,
    const float* __restrict__ aggr,
    const float* __restrict__ nW1, const float* __restrict__ nb1,
    const float* __restrict__ nW2, const float* __restrict__ nb2,
    float* __restrict__ out_n)   // [NODES, 128] f32
{
    const int t  = threadIdx.x;
    const int c  = t & 127;
    const int kh = t >> 7;

    unsigned int w1p[48];
    {
        const int k0 = kh * 96;
        #pragma unroll
        for (int j = 0; j < 48; ++j)
            w1p[j] = packh2(nW1[(size_t)(k0 + 2 * j) * NC + c],
                            nW1[(size_t)(k0 + 2 * j + 1) * NC + c]);
    }
    unsigned int w2p[32];
    {
        const int k0 = kh * 64;
        #pragma unroll
        for (int j = 0; j < 32; ++j)
            w2p[j] = packh2(nW2[(size_t)(k0 + 2 * j) * NC + c],
                            nW2[(size_t)(k0 + 2 * j + 1) * NC + c]);
    }
    const float b1 = nb1[c];
    const float b2 = nb2[c];

    __shared__ __align__(16) uint2        sbufp[48];
    __shared__ float                      red1[NC];
    __shared__ __align__(16) unsigned int hbufp[64];

    float4 x4a = make_float4(0.f, 0.f, 0.f, 0.f);
    if (t < 32)       x4a = ((const float4*)(xn + (size_t)blockIdx.x * NC))[t];
    else if (t < 48)  x4a = ((const float4*)(aggr + (size_t)blockIdx.x * EC))[t - 32];

    for (int v = blockIdx.x; v < NODES; v += gridDim.x) {
        const int vn    = v + gridDim.x;
        const int vload = (vn < NODES) ? vn : v;

        if (t < 48) {
            sbufp[t] = make_uint2(pkrtz(x4a.x, x4a.y), pkrtz(x4a.z, x4a.w));
            x4a = (t < 32)
                ? ((const float4*)(xn + (size_t)vload * NC))[t]
                : ((const float4*)(aggr + (size_t)vload * EC))[t - 32];
        }
        __syncthreads();

        float a0 = 0.f, a1 = 0.f;
        {
            const uint4* sp = ((const uint4*)sbufp) + kh * 12;
            #pragma unroll
            for (int j = 0; j < 12; ++j) {
                uint4 u = sp[j];
                a0 = FDOT2(u.x, w1p[4 * j + 0], a0);
                a1 = FDOT2(u.y, w1p[4 * j + 1], a1);
                a0 = FDOT2(u.z, w1p[4 * j + 2], a0);
                a1 = FDOT2(u.w, w1p[4 * j + 3], a1);
            }
        }
        float acc = a0 + a1;
        if (kh) red1[c] = acc;
        __syncthreads();

        if (!kh) {
            float h  = silu_f(acc + red1[c] + b1);
            float hx = __shfl_xor(h, 1);
            unsigned int hpk = (c & 1) ? pkrtz(hx, h) : pkrtz(h, hx);
            if (!(c & 1)) hbufp[c >> 1] = hpk;
        }
        __syncthreads();

        float d0 = 0.f, d1 = 0.f;
        {
            const uint4* hp4 = ((const uint4*)hbufp) + kh * 8;
            #pragma unroll
            for (int j = 0; j < 8; ++j) {
                uint4 u = hp4[j];
                d0 = FDOT2(u.x, w2p[4 * j + 0], d0);
                d1 = FDOT2(u.y, w2p[4 * j + 1], d1);
                d0 = FDOT2(u.z, w2p[4 * j + 2], d0);
                d1 = FDOT2(u.w, w2p[4 * j + 3], d1);
            }
        }
        float acc2 = d0 + d1;
        if (kh) red1[c] = acc2;
        __syncthreads();
        if (!kh) out_n[(size_t)v * NC + c] = acc2 + red1[c] + b2;
        __syncthreads();
    }
}

extern "C" void kernel_launch(void* const* d_in, const int* in_sizes, int n_in,
                              void* d_out, int out_size, void* d_ws, size_t ws_size,
                              hipStream_t stream) {
    const float* xn  = (const float*)d_in[0];
    const float* xe  = (const float*)d_in[1];
    const int*   ei  = (const int*)d_in[2];
    const float* eW1 = (const float*)d_in[3];
    const float* eb1 = (const float*)d_in[4];
    const float* eW2 = (const float*)d_in[5];
    const float* eb2 = (const float*)d_in[6];
    const float* nW1 = (const float*)d_in[7];
    const float* nb1 = (const float*)d_in[8];
    const float* nW2 = (const float*)d_in[9];
    const float* nb2 = (const float*)d_in[10];

    float* out_n = (float*)d_out;               // [50000,128] f32
    float* out_e = out_n + (size_t)NODES * NC;  // [800000,64] f32
    float* aggr  = (float*)d_ws;                // [50000,64] f32

    // PA/PB (f16) live in the out_n region (25.6 MB exactly); node_kernel
    // overwrites it at the very end, after edge_kernel has consumed them.
    unsigned short* pa = (unsigned short*)out_n;
    unsigned short* pb = pa + (size_t)NODES * NC;

    (void)hipMemsetAsync(aggr, 0, (size_t)NODES * O2E * sizeof(float), stream);

    hipLaunchKernelGGL(pre_kernel, dim3(1024), dim3(256), 0, stream,
                       xn, eW1, eb1, pa, pb);
    hipLaunchKernelGGL(edge_kernel, dim3(1024), dim3(256), 0, stream,
                       xe, ei, pa, pb, eW1, eW2, eb2, out_e, aggr);
    hipLaunchKernelGGL(node_kernel, dim3(1024), dim3(256), 0, stream,
                       xn, aggr, nW1, nb1, nW2, nb2, out_n);
}